// Round 11
// baseline (17723.589 us; speedup 1.0000x reference)
//
#include <hip/hip_runtime.h>
#include <math.h>

#define Bb 8
#define Tt 168
#define Nn 512
#define Cc 32
#define Ll 4
#define Kk 50
#define NCH 4
#define BPC 2                     // batches per chunk (chunk boundary = t==0, no cross-chunk reads)
#define BTc (BPC*Tt)              // 336
#define BTNc ((size_t)BTc*Nn)
#define BTCNc ((size_t)BTc*Cc*Nn)
#define BT (Bb*Tt)
#define BTN ((size_t)Bb*Tt*Nn)
#define BTCN ((size_t)Bb*Tt*Cc*Nn)
#define GRUB 64                   // GRU blocks: each owns 8 output cols, all batches

typedef __attribute__((ext_vector_type(8))) short short8v;
typedef __attribute__((ext_vector_type(4))) float f32x4;
typedef __attribute__((ext_vector_type(2))) float f32x2;

__device__ __forceinline__ float sigm(float v) { return 1.0f/(1.0f + expf(-v)); }

__device__ __forceinline__ unsigned int f2bf(float x) {   // RNE, returns bits in low 16
  unsigned int u = __float_as_uint(x);
  u = u + 0x7FFFu + ((u >> 16) & 1u);
  return u >> 16;
}
__device__ __forceinline__ float bf2f(unsigned int h) {
  return __uint_as_float(h << 16);
}

__device__ __forceinline__ float sysload(const float* p) {
  return __hip_atomic_load(p, __ATOMIC_RELAXED, __HIP_MEMORY_SCOPE_SYSTEM);
}
__device__ __forceinline__ void sysstore(float* p, float v) {
  __hip_atomic_store(p, v, __ATOMIC_RELAXED, __HIP_MEMORY_SCOPE_SYSTEM);
}
__device__ __forceinline__ int flagload(const int* p) {
  return __hip_atomic_load(p, __ATOMIC_RELAXED, __HIP_MEMORY_SCOPE_AGENT);
}
__device__ __forceinline__ void flagstore(int* p, int v) {
  __hip_atomic_store(p, v, __ATOMIC_RELAXED, __HIP_MEMORY_SCOPE_AGENT);
}

// cache-bypassing vector store (coherence-point data plane)
__device__ __forceinline__ void byp_store4(float* p, f32x4 v) {
  asm volatile("global_store_dwordx4 %0, %1, off sc0 sc1" :: "v"(p), "v"(v) : "memory");
}

// ---------------- pack GRU weights block-sliced: wpack[sl][c][kk], kk over [z|r|hx|hh] ----------------
__global__ void k_wt2(const float* __restrict__ zl, const float* __restrict__ rl,
                      const float* __restrict__ hl, float* __restrict__ wpack) {
  int idx = blockIdx.x*256 + threadIdx.x;       // 64*8*3072 = 1572864
  if (idx >= GRUB*8*3072) return;
  int kk = idx % 3072;
  int c  = (idx / 3072) & 7;
  int sl = idx / (3072*8);
  int ncol = sl*8 + c;
  float v;
  if (kk < 1024)      v = zl[ncol*1024 + kk];
  else if (kk < 2048) v = rl[ncol*1024 + (kk-1024)];
  else if (kk < 2560) v = hl[ncol*1024 + (kk-2048)];
  else                v = hl[ncol*1024 + 512 + (kk-2560)];
  wpack[idx] = v;
}

// ---------------- adaptive adjacency: softmax(relu(nv1@nv2), axis=1) ----------------
__global__ void k_adp(const float* __restrict__ nv1, const float* __restrict__ nv2,
                      float* __restrict__ adp) {
  int i = blockIdx.x;
  __shared__ float row[512];
  __shared__ float red[256];
  float v1[10];
  #pragma unroll
  for (int k=0;k<10;k++) v1[k] = nv1[i*10+k];
  for (int jj = threadIdx.x; jj < 512; jj += 256) {
    float s = 0.f;
    #pragma unroll
    for (int k=0;k<10;k++) s += v1[k]*nv2[k*Nn + jj];
    row[jj] = fmaxf(s, 0.f);
  }
  __syncthreads();
  float m = fmaxf(row[threadIdx.x], row[threadIdx.x+256]);
  red[threadIdx.x] = m; __syncthreads();
  for (int s=128; s>0; s>>=1) { if (threadIdx.x < s) red[threadIdx.x] = fmaxf(red[threadIdx.x], red[threadIdx.x+s]); __syncthreads(); }
  float mx = red[0]; __syncthreads();
  float e0 = expf(row[threadIdx.x]      - mx);
  float e1 = expf(row[threadIdx.x+256]  - mx);
  red[threadIdx.x] = e0 + e1; __syncthreads();
  for (int s=128; s>0; s>>=1) { if (threadIdx.x < s) red[threadIdx.x] += red[threadIdx.x+s]; __syncthreads(); }
  float inv = 1.f/red[0];
  adp[(size_t)i*Nn + threadIdx.x]       = e0*inv;
  adp[(size_t)i*Nn + threadIdx.x + 256] = e1*inv;
}

// ---------------- split supports to transposed bf16 hi/lo: ShiT[s][n][k] ----------------
__global__ void k_sprep(const float* __restrict__ sup0, const float* __restrict__ sup1,
                        const float* __restrict__ adp,
                        unsigned short* __restrict__ ShiT, unsigned short* __restrict__ SloT) {
  int idx = blockIdx.x*256 + threadIdx.x;
  if (idx >= 3*512*512) return;
  int s = idx >> 18;
  int rem = idx & 262143;
  int n = rem >> 9, k = rem & 511;
  const float* S = (s==0) ? sup0 : (s==1) ? sup1 : adp;
  float v = S[k*512 + n];
  unsigned int h = f2bf(v);
  float lo = v - bf2f(h);
  ShiT[idx] = (unsigned short)h;
  SloT[idx] = (unsigned short)f2bf(lo);
}

// ---------------- input transform: x = conv1x1(input[[0,3,5,6]]) -> (B,T,C,N) ----------------
__global__ void k_intransform(const float* __restrict__ input, const float* __restrict__ skw,
                              const float* __restrict__ skb, float* __restrict__ x) {
  size_t idx = (size_t)blockIdx.x*256 + threadIdx.x;
  if (idx >= BTN) return;
  int n = idx & 511;
  size_t bt = idx >> 9;
  int b = (int)(bt / Tt), t = (int)(bt % Tt);
  size_t chs = (size_t)Tt*Nn;
  size_t base = (((size_t)b*7)*Tt + t)*Nn + n;
  float v0 = input[base + 0*chs];
  float v3 = input[base + 3*chs];
  float v5 = input[base + 5*chs];
  float v6 = input[base + 6*chs];
  float* xp = x + bt*Cc*Nn + n;
  #pragma unroll
  for (int c=0;c<32;c++)
    xp[(size_t)c*Nn] = skb[c] + skw[c*4+0]*v0 + skw[c*4+1]*v3 + skw[c*4+2]*v5 + skw[c*4+3]*v6;
}

// ---------------- fused filter/gate conv1x2 -> xg_q ; gout_q = W0@xg + bias (chunk-local) ----------------
__launch_bounds__(256)
__global__ void k_fgconv(const float* __restrict__ x, const float* __restrict__ fw,
                         const float* __restrict__ fb, const float* __restrict__ gw,
                         const float* __restrict__ gb, const float* __restrict__ gcwl,
                         const float* __restrict__ gcb,
                         float* __restrict__ xg, float* __restrict__ gout, int chunk) {
  __shared__ float sfw[2048], sgw[2048], sw0[1024], sfb[32], sgb[32], sgcb[32];
  for (int l = threadIdx.x; l < 2048; l += 256) { sfw[l] = fw[l]; sgw[l] = gw[l]; }
  for (int l = threadIdx.x; l < 1024; l += 256) sw0[l] = gcwl[(l>>5)*224 + (l&31)];
  if (threadIdx.x < 32) {
    sfb[threadIdx.x] = fb[threadIdx.x];
    sgb[threadIdx.x] = gb[threadIdx.x];
    sgcb[threadIdx.x] = gcb[threadIdx.x];
  }
  __syncthreads();
  size_t idx = (size_t)blockIdx.x*256 + threadIdx.x;
  if (idx >= BTNc) return;
  int n = idx & 511;
  size_t btl = idx >> 9;
  int t = (int)(btl % Tt);
  size_t btg = (size_t)chunk*BTc + btl;
  const float* xp = x + btg*Cc*Nn + n;
  float xl[32], xr[32];
  #pragma unroll
  for (int c=0;c<32;c++) xr[c] = xp[(size_t)c*Nn];
  if (t == 0) {
    #pragma unroll
    for (int c=0;c<32;c++) xl[c] = 0.f;
  } else {
    const float* xq = xp - (size_t)Cc*Nn;
    #pragma unroll
    for (int c=0;c<32;c++) xl[c] = xq[(size_t)c*Nn];
  }
  float xgv[32];
  for (int c=0;c<32;c++) {
    float f = sfb[c], g = sgb[c];
    #pragma unroll
    for (int cp=0;cp<32;cp++) {
      f += xl[cp]*sfw[(c*32+cp)*2] + xr[cp]*sfw[(c*32+cp)*2+1];
      g += xl[cp]*sgw[(c*32+cp)*2] + xr[cp]*sgw[(c*32+cp)*2+1];
    }
    xgv[c] = tanhf(f) * sigm(g);
  }
  float* xgp = xg + btl*Cc*Nn + n;
  #pragma unroll
  for (int c=0;c<32;c++) xgp[(size_t)c*Nn] = xgv[c];
  float* gp = gout + btl*Cc*Nn + n;
  for (int o=0;o<32;o++) {
    float s = sgcb[o];
    #pragma unroll
    for (int c=0;c<32;c++) s += sw0[o*32+c]*xgv[c];
    gp[(size_t)o*Nn] = s;
  }
}

// ---------------- fused support chain: gout += ((W1@X) + (W2@X)@A)@A per support ----------------
// Associativity: W1@(X@A) + W2@(X@A@A) = ((W1@X) + (W2@X)@A)@A. One block per bt;
// intermediates in LDS pre-split to bf16 hi/lo at write (readers: pure ds_read_b128);
// support B-fragments gathered directly from L2-resident ShiT/SloT. No W-mix epilogue,
// no tmp1 global round trip.
__launch_bounds__(512, 2)
__global__ void k_supfused(const float* __restrict__ X,
                           const unsigned short* __restrict__ ShiTall,
                           const unsigned short* __restrict__ SloTall,
                           const float* __restrict__ gcw,
                           float* __restrict__ gout) {
  __shared__ __align__(16) unsigned char pool[74752];
  unsigned short* sRhi = (unsigned short*)pool;            // [32][520]
  unsigned short* sRlo = (unsigned short*)(pool + 33280);  // [32][520]
  float*          sG   = (float*)pool;                     // [32][516] alias (epilogue only)
  unsigned short* sWhi = (unsigned short*)(pool + 66560);  // [2][32][32]
  unsigned short* sWlo = (unsigned short*)(pool + 70656);  // [2][32][32]

  const int tid  = threadIdx.x;
  const int bt   = blockIdx.x;
  const int lane = tid & 63;
  const int wv   = tid >> 6;           // 8 waves, 64 cols each
  const int n0w  = wv*64;
  const int l15  = lane & 15;
  const int kb0  = (lane >> 4)*8;      // k-offset within 32-chunk
  const float* Xb = X + (size_t)bt*Cc*Nn;

  for (int s = 0; s < 3; s++) {
    const unsigned short* Shi = ShiTall + (size_t)s*262144;
    const unsigned short* Slo = SloTall + (size_t)s*262144;
    __syncthreads();   // sR/sW free of prior readers
    // stage W1 (slot0, pslot 2s+1), W2 (slot1, pslot 2s+2) as bf16 hi/lo
    for (int i = tid; i < 2048; i += 512) {
      int slot = i >> 10, idx = i & 1023;
      int o = idx >> 5, c = idx & 31;
      float v = gcw[o*224 + (2*s + 1 + slot)*32 + c];
      unsigned int h = f2bf(v);
      sWhi[i] = (unsigned short)h;
      sWlo[i] = (unsigned short)f2bf(v - bf2f(h));
    }
    __syncthreads();

    f32x4 acc[2][4];
    // ---- build X B-frags (K=32, c-dim): col = n0w+ct*16+l15, k = kb0..kb0+8 ----
    short8v xbhi[4], xblo[4];
    #pragma unroll
    for (int ct = 0; ct < 4; ct++) {
      int col = n0w + ct*16 + l15;
      #pragma unroll
      for (int e = 0; e < 8; e++) {
        float v = Xb[(size_t)(kb0 + e)*Nn + col];
        unsigned int h = f2bf(v);
        xbhi[ct][e] = (short)h;
        xblo[ct][e] = (short)f2bf(v - bf2f(h));
      }
    }
    // ---- P = W2@X ----
    #pragma unroll
    for (int rt = 0; rt < 2; rt++) {
      int o = rt*16 + l15;
      short8v whi = *reinterpret_cast<const short8v*>(&sWhi[1024 + o*32 + kb0]);
      short8v wlo = *reinterpret_cast<const short8v*>(&sWlo[1024 + o*32 + kb0]);
      #pragma unroll
      for (int ct = 0; ct < 4; ct++) {
        f32x4 a = {0.f,0.f,0.f,0.f};
        a = __builtin_amdgcn_mfma_f32_16x16x32_bf16(whi, xbhi[ct], a, 0, 0, 0);
        a = __builtin_amdgcn_mfma_f32_16x16x32_bf16(whi, xblo[ct], a, 0, 0, 0);
        a = __builtin_amdgcn_mfma_f32_16x16x32_bf16(wlo, xbhi[ct], a, 0, 0, 0);
        acc[rt][ct] = a;
      }
    }
    // write P -> sR (hi/lo split at write)
    #pragma unroll
    for (int rt = 0; rt < 2; rt++) {
      #pragma unroll
      for (int ct = 0; ct < 4; ct++) {
        int col = n0w + ct*16 + l15;
        int rb  = rt*16 + (lane >> 4)*4;
        #pragma unroll
        for (int e = 0; e < 4; e++) {
          float v = acc[rt][ct][e];
          unsigned int h = f2bf(v);
          sRhi[(rb+e)*520 + col] = (unsigned short)h;
          sRlo[(rb+e)*520 + col] = (unsigned short)f2bf(v - bf2f(h));
        }
      }
    }
    __syncthreads();
    // ---- T = P@A + W1@X ----
    #pragma unroll
    for (int rt = 0; rt < 2; rt++)
      #pragma unroll
      for (int ct = 0; ct < 4; ct++) acc[rt][ct] = (f32x4){0.f,0.f,0.f,0.f};
    for (int kc = 0; kc < 16; kc++) {
      int kb = kc*32 + kb0;
      short8v bhi[4], blo[4];
      #pragma unroll
      for (int ct = 0; ct < 4; ct++) {
        int col = n0w + ct*16 + l15;
        bhi[ct] = *reinterpret_cast<const short8v*>(Shi + (size_t)col*512 + kb);
        blo[ct] = *reinterpret_cast<const short8v*>(Slo + (size_t)col*512 + kb);
      }
      #pragma unroll
      for (int rt = 0; rt < 2; rt++) {
        int r = rt*16 + l15;
        short8v ahi = *reinterpret_cast<const short8v*>(&sRhi[r*520 + kb]);
        short8v alo = *reinterpret_cast<const short8v*>(&sRlo[r*520 + kb]);
        #pragma unroll
        for (int ct = 0; ct < 4; ct++) {
          acc[rt][ct] = __builtin_amdgcn_mfma_f32_16x16x32_bf16(ahi, bhi[ct], acc[rt][ct], 0, 0, 0);
          acc[rt][ct] = __builtin_amdgcn_mfma_f32_16x16x32_bf16(ahi, blo[ct], acc[rt][ct], 0, 0, 0);
          acc[rt][ct] = __builtin_amdgcn_mfma_f32_16x16x32_bf16(alo, bhi[ct], acc[rt][ct], 0, 0, 0);
        }
      }
    }
    // accumulate W1@X into same acc
    #pragma unroll
    for (int rt = 0; rt < 2; rt++) {
      int o = rt*16 + l15;
      short8v whi = *reinterpret_cast<const short8v*>(&sWhi[o*32 + kb0]);
      short8v wlo = *reinterpret_cast<const short8v*>(&sWlo[o*32 + kb0]);
      #pragma unroll
      for (int ct = 0; ct < 4; ct++) {
        acc[rt][ct] = __builtin_amdgcn_mfma_f32_16x16x32_bf16(whi, xbhi[ct], acc[rt][ct], 0, 0, 0);
        acc[rt][ct] = __builtin_amdgcn_mfma_f32_16x16x32_bf16(whi, xblo[ct], acc[rt][ct], 0, 0, 0);
        acc[rt][ct] = __builtin_amdgcn_mfma_f32_16x16x32_bf16(wlo, xbhi[ct], acc[rt][ct], 0, 0, 0);
      }
    }
    __syncthreads();   // all reads of P done before overwrite
    #pragma unroll
    for (int rt = 0; rt < 2; rt++) {
      #pragma unroll
      for (int ct = 0; ct < 4; ct++) {
        int col = n0w + ct*16 + l15;
        int rb  = rt*16 + (lane >> 4)*4;
        #pragma unroll
        for (int e = 0; e < 4; e++) {
          float v = acc[rt][ct][e];
          unsigned int h = f2bf(v);
          sRhi[(rb+e)*520 + col] = (unsigned short)h;
          sRlo[(rb+e)*520 + col] = (unsigned short)f2bf(v - bf2f(h));
        }
      }
    }
    __syncthreads();
    // ---- G = T@A ----
    #pragma unroll
    for (int rt = 0; rt < 2; rt++)
      #pragma unroll
      for (int ct = 0; ct < 4; ct++) acc[rt][ct] = (f32x4){0.f,0.f,0.f,0.f};
    for (int kc = 0; kc < 16; kc++) {
      int kb = kc*32 + kb0;
      short8v bhi[4], blo[4];
      #pragma unroll
      for (int ct = 0; ct < 4; ct++) {
        int col = n0w + ct*16 + l15;
        bhi[ct] = *reinterpret_cast<const short8v*>(Shi + (size_t)col*512 + kb);
        blo[ct] = *reinterpret_cast<const short8v*>(Slo + (size_t)col*512 + kb);
      }
      #pragma unroll
      for (int rt = 0; rt < 2; rt++) {
        int r = rt*16 + l15;
        short8v ahi = *reinterpret_cast<const short8v*>(&sRhi[r*520 + kb]);
        short8v alo = *reinterpret_cast<const short8v*>(&sRlo[r*520 + kb]);
        #pragma unroll
        for (int ct = 0; ct < 4; ct++) {
          acc[rt][ct] = __builtin_amdgcn_mfma_f32_16x16x32_bf16(ahi, bhi[ct], acc[rt][ct], 0, 0, 0);
          acc[rt][ct] = __builtin_amdgcn_mfma_f32_16x16x32_bf16(ahi, blo[ct], acc[rt][ct], 0, 0, 0);
          acc[rt][ct] = __builtin_amdgcn_mfma_f32_16x16x32_bf16(alo, bhi[ct], acc[rt][ct], 0, 0, 0);
        }
      }
    }
    __syncthreads();   // all reads of T done before sG alias write
    #pragma unroll
    for (int rt = 0; rt < 2; rt++) {
      #pragma unroll
      for (int ct = 0; ct < 4; ct++) {
        int col = n0w + ct*16 + l15;
        int rb  = rt*16 + (lane >> 4)*4;
        sG[(rb+0)*516 + col] = acc[rt][ct][0];
        sG[(rb+1)*516 + col] = acc[rt][ct][1];
        sG[(rb+2)*516 + col] = acc[rt][ct][2];
        sG[(rb+3)*516 + col] = acc[rt][ct][3];
      }
    }
    __syncthreads();
    // ---- gout += G (coalesced float4 RMW) ----
    for (int j = tid; j < 32*128; j += 512) {
      int row = j >> 7, c4 = (j & 127)*4;
      float* gp = gout + (size_t)bt*Cc*Nn + (size_t)row*Nn + c4;
      float4 cur = *reinterpret_cast<float4*>(gp);
      const float* gs = sG + row*516 + c4;
      cur.x += gs[0]; cur.y += gs[1]; cur.z += gs[2]; cur.w += gs[3];
      *reinterpret_cast<float4*>(gp) = cur;
    }
  }
}

// ---------------- skip gather: skipK[b,k,c,t] (+)= xg_q[btl,c,node] ----------------
__global__ void k_skipgather(const float* __restrict__ xg, const int* __restrict__ miss,
                             float* __restrict__ skipK, int chunk, int first) {
  int idx = blockIdx.x*256 + threadIdx.x;
  if (idx >= BPC*Kk*Tt) return;
  int t = idx % Tt;
  int k = (idx / Tt) % Kk;
  int bloc = idx / (Tt*Kk);
  int bg = chunk*BPC + bloc;
  int node = miss[bg*Kk + k];
  const float* xp = xg + (((size_t)bloc*Tt + t)*Cc)*Nn + node;
  float* sp = skipK + (((size_t)bg*Kk + k)*Cc)*Tt + t;
  #pragma unroll
  for (int c=0;c<32;c++) {
    float v = xp[(size_t)c*Nn];
    sp[(size_t)c*Tt] = first ? v : (sp[(size_t)c*Tt] + v);
  }
}

// ---------------- fused ingru + xfold: Xs = iw@gout + ib ; x += gout (one gout pass) ----------------
__global__ void k_ingruxf(const float* __restrict__ gout, const float* __restrict__ iw,
                          const float* __restrict__ ib2, float* __restrict__ Xs,
                          float* __restrict__ x, int chunk) {
  size_t idx = (size_t)blockIdx.x*256 + threadIdx.x;
  if (idx >= BTNc) return;
  int n = idx & 511;
  size_t btl = idx >> 9;
  int b = chunk*BPC + (int)(btl / Tt), t = (int)(btl % Tt);
  const float* gp = gout + btl*Cc*Nn + n;
  float* xp = x + ((size_t)chunk*BTc + btl)*Cc*Nn + n;
  float s = ib2[0];
  #pragma unroll
  for (int c=0;c<Cc;c++) {
    float g = gp[(size_t)c*Nn];
    s += iw[c]*g;
    xp[(size_t)c*Nn] += g;
  }
  Xs[((size_t)t*Bb + b)*Nn + n] = s;
}

// ---------------- GRU v7: wave-decoupled (per-batch flags, no __syncthreads in t-loop) ----------------
__launch_bounds__(512, 1)
__global__ void k_gru7(const float* __restrict__ Xs, const float* __restrict__ input,
                       const float* __restrict__ wpack,
                       const float* __restrict__ zb, const float* __restrict__ rb,
                       const float* __restrict__ hb,
                       float* __restrict__ xh_g,      // [b][ xin 0:512 | h 512:1024 ]
                       float* __restrict__ rh_g,      // [b][512]
                       float* __restrict__ outs,
                       int* __restrict__ flags) {     // [(b*64+sl)*32]
  __shared__ float wl[8*3072];   // 96KB weights only
  const int tid = threadIdx.x;
  const int sl  = blockIdx.x;
  const int n0  = sl*8;
  const int b   = tid >> 6;      // wave = batch
  const int q   = tid & 63;

  {
    const float4* src = reinterpret_cast<const float4*>(wpack + (size_t)sl*24576);
    float4* dst = reinterpret_cast<float4*>(wl);
    #pragma unroll 4
    for (int i = tid; i < 6144; i += 512) dst[i] = src[i];
  }
  if (q < 8) {
    int nn = n0 + q;
    float Xi = Xs[(size_t)b*Nn + nn];
    float Mi = input[(((size_t)b*7+1)*Tt + 0)*Nn + nn];
    sysstore(xh_g + b*1024 + 512 + nn, 0.f);
    sysstore(xh_g + b*1024 + nn, sigm(Xi*Mi));
  }
  __syncthreads();
  asm volatile("s_waitcnt vmcnt(0)" ::: "memory");
  if (q == 0) flagstore(flags + (b*64 + sl)*32, 1);

  const int* pollfl = flags + (b*64 + q)*32;
  int* myfl = flags + (b*64 + sl)*32;

  float zbv[8], rbv[8], hbv[8];
  #pragma unroll
  for (int c=0;c<8;c++) { zbv[c]=zb[n0+c]; rbv[c]=rb[n0+c]; hbv[c]=hb[n0+c]; }

  const float* bp = xh_g + b*1024;
  const float* rp = rh_g + b*512;

  for (int t = 0; t < Tt; t++) {
    float4 xiA, xiB, miA, miB;
    {
      int tp = (t+1 < Tt) ? (t+1) : t;
      const float* xsp = Xs + ((size_t)tp*Bb + b)*Nn + n0;
      const float* mip = input + (((size_t)b*7+1)*Tt + tp)*Nn + n0;
      xiA = *reinterpret_cast<const float4*>(xsp);
      xiB = *reinterpret_cast<const float4*>(xsp + 4);
      miA = *reinterpret_cast<const float4*>(mip);
      miB = *reinterpret_cast<const float4*>(mip + 4);
    }
    {
      int tgt = 1 + 2*t;
      while (!__all(flagload(pollfl) >= tgt)) __builtin_amdgcn_s_sleep(1);
    }
    f32x2 xv[8]; f32x4 h0v, h1v;
    asm volatile(
      "global_load_dwordx2 %0, %10, off sc0 sc1\n\t"
      "global_load_dwordx2 %1, %11, off sc0 sc1\n\t"
      "global_load_dwordx2 %2, %12, off sc0 sc1\n\t"
      "global_load_dwordx2 %3, %13, off sc0 sc1\n\t"
      "global_load_dwordx2 %4, %14, off sc0 sc1\n\t"
      "global_load_dwordx2 %5, %15, off sc0 sc1\n\t"
      "global_load_dwordx2 %6, %16, off sc0 sc1\n\t"
      "global_load_dwordx2 %7, %17, off sc0 sc1\n\t"
      "global_load_dwordx4 %8, %18, off sc0 sc1\n\t"
      "global_load_dwordx4 %9, %19, off sc0 sc1\n\t"
      "s_waitcnt vmcnt(0)"
      : "=&v"(xv[0]), "=&v"(xv[1]), "=&v"(xv[2]), "=&v"(xv[3]),
        "=&v"(xv[4]), "=&v"(xv[5]), "=&v"(xv[6]), "=&v"(xv[7]),
        "=&v"(h0v), "=&v"(h1v)
      : "v"(bp + 0*128 + q*2), "v"(bp + 1*128 + q*2), "v"(bp + 2*128 + q*2), "v"(bp + 3*128 + q*2),
        "v"(bp + 4*128 + q*2), "v"(bp + 5*128 + q*2), "v"(bp + 6*128 + q*2), "v"(bp + 7*128 + q*2),
        "v"(bp + 512 + n0), "v"(bp + 512 + n0 + 4)
      : "memory");
    float hold[8] = {h0v.x, h0v.y, h0v.z, h0v.w, h1v.x, h1v.y, h1v.z, h1v.w};
    float az[8], ar[8], ax[8];
    #pragma unroll
    for (int c=0;c<8;c++) { az[c]=0.f; ar[c]=0.f; ax[c]=0.f; }
    #pragma unroll
    for (int i = 0; i < 8; i++) {
      int k = i*128 + q*2;
      #pragma unroll
      for (int c = 0; c < 8; c++) {
        float2 wz = *reinterpret_cast<const float2*>(wl + c*3072 + k);
        float2 wr = *reinterpret_cast<const float2*>(wl + c*3072 + 1024 + k);
        az[c] += xv[i].x*wz.x + xv[i].y*wz.y;
        ar[c] += xv[i].x*wr.x + xv[i].y*wr.y;
      }
    }
    #pragma unroll
    for (int i = 0; i < 4; i++) {
      int k = i*128 + q*2;
      #pragma unroll
      for (int c = 0; c < 8; c++) {
        float2 wx = *reinterpret_cast<const float2*>(wl + c*3072 + 2048 + k);
        ax[c] += xv[i].x*wx.x + xv[i].y*wx.y;
      }
    }
    #pragma unroll
    for (int d = 1; d < 64; d <<= 1) {
      #pragma unroll
      for (int c = 0; c < 8; c++) {
        az[c] += __shfl_xor(az[c], d);
        ar[c] += __shfl_xor(ar[c], d);
        ax[c] += __shfl_xor(ax[c], d);
      }
    }
    float zs[8], rh[8];
    #pragma unroll
    for (int c = 0; c < 8; c++) {
      zs[c] = sigm(az[c] + zbv[c]);
      float r = sigm(ar[c] + rbv[c]);
      rh[c] = r * hold[c];
    }
    if (q == 0) {
      f32x4 r0 = {rh[0],rh[1],rh[2],rh[3]};
      f32x4 r1 = {rh[4],rh[5],rh[6],rh[7]};
      byp_store4(rh_g + b*512 + n0,     r0);
      byp_store4(rh_g + b*512 + n0 + 4, r1);
      asm volatile("s_waitcnt vmcnt(0)" ::: "memory");
      flagstore(myfl, 2 + 2*t);
    }
    {
      int tgt = 2 + 2*t;
      while (!__all(flagload(pollfl) >= tgt)) __builtin_amdgcn_s_sleep(1);
    }
    f32x2 rv[4];
    asm volatile(
      "global_load_dwordx2 %0, %4, off sc0 sc1\n\t"
      "global_load_dwordx2 %1, %5, off sc0 sc1\n\t"
      "global_load_dwordx2 %2, %6, off sc0 sc1\n\t"
      "global_load_dwordx2 %3, %7, off sc0 sc1\n\t"
      "s_waitcnt vmcnt(0)"
      : "=&v"(rv[0]), "=&v"(rv[1]), "=&v"(rv[2]), "=&v"(rv[3])
      : "v"(rp + 0*128 + q*2), "v"(rp + 1*128 + q*2), "v"(rp + 2*128 + q*2), "v"(rp + 3*128 + q*2)
      : "memory");
    float ah[8];
    #pragma unroll
    for (int c=0;c<8;c++) ah[c]=0.f;
    #pragma unroll
    for (int i = 0; i < 4; i++) {
      int k = i*128 + q*2;
      #pragma unroll
      for (int c = 0; c < 8; c++) {
        float2 wh = *reinterpret_cast<const float2*>(wl + c*3072 + 2560 + k);
        ah[c] += rv[i].x*wh.x + rv[i].y*wh.y;
      }
    }
    #pragma unroll
    for (int d = 1; d < 64; d <<= 1) {
      #pragma unroll
      for (int c = 0; c < 8; c++) ah[c] += __shfl_xor(ah[c], d);
    }
    float hn[8];
    #pragma unroll
    for (int c = 0; c < 8; c++) {
      float ht = tanhf(ax[c] + ah[c] + hbv[c]);
      hn[c] = (1.f - zs[c])*hold[c] + zs[c]*ht;
    }
    if (q == 0) {
      f32x4 h0 = {hn[0],hn[1],hn[2],hn[3]};
      f32x4 h1 = {hn[4],hn[5],hn[6],hn[7]};
      *reinterpret_cast<f32x4*>(&outs[((size_t)t*Bb + b)*Nn + n0])     = h0;
      *reinterpret_cast<f32x4*>(&outs[((size_t)t*Bb + b)*Nn + n0 + 4]) = h1;
      byp_store4(xh_g + b*1024 + 512 + n0,     h0);
      byp_store4(xh_g + b*1024 + 512 + n0 + 4, h1);
      if (t+1 < Tt) {
        f32x4 x0, x1;
        x0.x = sigm(xiA.x*miA.x + hn[0]*(1.f - miA.x));
        x0.y = sigm(xiA.y*miA.y + hn[1]*(1.f - miA.y));
        x0.z = sigm(xiA.z*miA.z + hn[2]*(1.f - miA.z));
        x0.w = sigm(xiA.w*miA.w + hn[3]*(1.f - miA.w));
        x1.x = sigm(xiB.x*miB.x + hn[4]*(1.f - miB.x));
        x1.y = sigm(xiB.y*miB.y + hn[5]*(1.f - miB.y));
        x1.z = sigm(xiB.z*miB.z + hn[6]*(1.f - miB.z));
        x1.w = sigm(xiB.w*miB.w + hn[7]*(1.f - miB.w));
        byp_store4(xh_g + b*1024 + n0,     x0);
        byp_store4(xh_g + b*1024 + n0 + 4, x1);
      }
      asm volatile("s_waitcnt vmcnt(0)" ::: "memory");
      flagstore(myfl, 3 + 2*t);
    }
  }
}

// ---------------- x += outs*rw + rb (after GRU) ----------------
__global__ void k_xre(float* __restrict__ x, const float* __restrict__ outs,
                      const float* __restrict__ rw, const float* __restrict__ rb2) {
  size_t idx = (size_t)blockIdx.x*256 + threadIdx.x;
  if (idx >= BTCN) return;
  int n = idx & 511;
  int c = (int)((idx >> 9) & 31);
  size_t bt = idx >> 14;
  int b = (int)(bt / Tt), t = (int)(bt % Tt);
  float o = outs[((size_t)t*Bb + b)*Nn + n];
  x[idx] += o*rw[c] + rb2[c];
}

// ---------------- head: relu(skipK) -> end1 relu -> end2 ----------------
__launch_bounds__(256)
__global__ void k_head(const float* __restrict__ skipK,
                       const float* __restrict__ e1w, const float* __restrict__ e1b,
                       const float* __restrict__ e2w, const float* __restrict__ e2b,
                       float* __restrict__ out) {
  __shared__ float sw[2048], sb[64], s2[64];
  for (int l = threadIdx.x; l < 2048; l += 256) sw[l] = e1w[l];
  if (threadIdx.x < 64) { sb[threadIdx.x] = e1b[threadIdx.x]; s2[threadIdx.x] = e2w[threadIdx.x]; }
  __syncthreads();
  int idx = blockIdx.x*256 + threadIdx.x;
  if (idx >= Bb*Kk*Tt) return;
  int t = idx % Tt;
  int k = (idx / Tt) % Kk;
  int b = idx / (Tt*Kk);
  const float* sp = skipK + (((size_t)b*Kk + k)*Cc)*Tt + t;
  float in[32];
  #pragma unroll
  for (int c=0;c<32;c++) in[c] = fmaxf(sp[(size_t)c*Tt], 0.f);
  float acc = e2b[0];
  for (int o=0;o<64;o++) {
    float s = sb[o];
    #pragma unroll
    for (int c=0;c<32;c++) s += sw[o*32+c]*in[c];
    acc += s2[o]*fmaxf(s, 0.f);
  }
  out[idx] = acc;
}

extern "C" void kernel_launch(void* const* d_in, const int* in_sizes, int n_in,
                              void* d_out, int out_size, void* d_ws, size_t ws_size,
                              hipStream_t stream) {
  const float* input = (const float*)d_in[0];
  const int*   miss  = (const int*)  d_in[1];
  const float* sup0  = (const float*)d_in[2];
  const float* sup1  = (const float*)d_in[3];
  const float* nv1   = (const float*)d_in[4];
  const float* nv2   = (const float*)d_in[5];
  const float* skw   = (const float*)d_in[6];
  const float* skb   = (const float*)d_in[7];
  const float* fw    = (const float*)d_in[8];
  const float* fb    = (const float*)d_in[9];
  const float* gw    = (const float*)d_in[10];
  const float* gb    = (const float*)d_in[11];
  const float* gcw   = (const float*)d_in[12];
  const float* gcb   = (const float*)d_in[13];
  const float* iw    = (const float*)d_in[14];
  const float* ib2   = (const float*)d_in[15];
  const float* rw    = (const float*)d_in[16];
  const float* rb2   = (const float*)d_in[17];
  const float* zl    = (const float*)d_in[18];
  const float* zb    = (const float*)d_in[19];
  const float* rl    = (const float*)d_in[20];
  const float* rb    = (const float*)d_in[21];
  const float* hl    = (const float*)d_in[22];
  const float* hb    = (const float*)d_in[23];
  const float* e1w   = (const float*)d_in[24];
  const float* e1b   = (const float*)d_in[25];
  const float* e2w   = (const float*)d_in[26];
  const float* e2b   = (const float*)d_in[27];
  float* out = (float*)d_out;

  float* p     = (float*)d_ws;
  float* x     = p; p += BTCN;
  float* xg    = p; p += BTCNc;
  float* gout  = p; p += BTCNc;
  float* skipK = p; p += (size_t)Bb*Kk*Cc*Tt;
  float* adp   = p; p += (size_t)Nn*Nn;
  float* wpack = p; p += (size_t)GRUB*8*3072;
  unsigned short* ShiT = (unsigned short*)p; p += (size_t)(3*512*512)/2;
  unsigned short* SloT = (unsigned short*)p; p += (size_t)(3*512*512)/2;
  float* Xs    = p; p += (size_t)Tt*Bb*Nn;
  float* outs  = p; p += (size_t)Tt*Bb*Nn;
  float* xh_g  = p; p += Bb*1024;
  float* rh_g  = p; p += Bb*512;
  int*   flags = (int*)p; p += (size_t)Bb*GRUB*32;

  k_wt2<<<(GRUB*8*3072 + 255)/256, 256, 0, stream>>>(zl, rl, hl, wpack);
  k_adp<<<Nn, 256, 0, stream>>>(nv1, nv2, adp);
  k_sprep<<<(3*512*512 + 255)/256, 256, 0, stream>>>(sup0, sup1, adp, ShiT, SloT);
  k_intransform<<<(int)((BTN + 255)/256), 256, 0, stream>>>(input, skw, skb, x);

  for (int layer = 0; layer < Ll; layer++) {
    for (int chunk = 0; chunk < NCH; chunk++) {
      k_fgconv<<<(int)((BTNc + 255)/256), 256, 0, stream>>>(
          x, fw + layer*2048, fb + layer*32, gw + layer*2048, gb + layer*32,
          gcw + layer*32*224, gcb + layer*32, xg, gout, chunk);
      k_supfused<<<dim3(BTc), dim3(512), 0, stream>>>(
          xg, ShiT, SloT, gcw + layer*32*224, gout);
      k_skipgather<<<(BPC*Kk*Tt + 255)/256, 256, 0, stream>>>(xg, miss, skipK, chunk, layer == 0 ? 1 : 0);
      k_ingruxf<<<(int)((BTNc + 255)/256), 256, 0, stream>>>(gout, iw, ib2, Xs, x, chunk);
    }
    (void)hipMemsetAsync(flags, 0, (size_t)Bb*GRUB*32*sizeof(int), stream);
    k_gru7<<<dim3(GRUB), dim3(512), 0, stream>>>(
        Xs, input, wpack, zb, rb, hb, xh_g, rh_g, outs, flags);
    k_xre<<<(int)((BTCN + 255)/256), 256, 0, stream>>>(x, outs, rw, rb2);
  }
  k_head<<<(Bb*Kk*Tt + 255)/256, 256, 0, stream>>>(skipK, e1w, e1b, e2w, e2b, out);
}